// Round 13
// baseline (411.740 us; speedup 1.0000x reference)
//
#include <hip/hip_runtime.h>
#include <hip/hip_bf16.h>

#define THREADS 256
#define HP 136     // padded LDS row stride (shorts) for h rows

typedef float f32x4 __attribute__((ext_vector_type(4)));
typedef short s16x8 __attribute__((ext_vector_type(8)));

static __device__ __forceinline__ short f2b(float x) {
    return __builtin_bit_cast(short, __float2bfloat16(x));
}
static __device__ __forceinline__ float b2f(short u) {
    unsigned int v = ((unsigned int)(unsigned short)u) << 16;
    return __builtin_bit_cast(float, v);
}
static __device__ __forceinline__ void split8(const f32x4 a, const f32x4 b, s16x8& hi, s16x8& lo) {
    #pragma unroll
    for (int j = 0; j < 4; ++j) {
        short h0 = f2b(a[j]); hi[j]   = h0; lo[j]   = f2b(a[j] - b2f(h0));
        short h1 = f2b(b[j]); hi[j+4] = h1; lo[j+4] = f2b(b[j] - b2f(h1));
    }
}
static __device__ __forceinline__ s16x8 cvt8(const f32x4 a, const f32x4 b) {
    s16x8 r;
    r[0]=f2b(a[0]); r[1]=f2b(a[1]); r[2]=f2b(a[2]); r[3]=f2b(a[3]);
    r[4]=f2b(b[0]); r[5]=f2b(b[1]); r[6]=f2b(b[2]); r[7]=f2b(b[3]);
    return r;
}
static __device__ __forceinline__ float sigm(float x) { return 1.0f / (1.0f + __expf(-x)); }

#define MFMA16(A,B,C) __builtin_amdgcn_mfma_f32_16x16x32_bf16((A),(B),(C),0,0,0)

// Raw barrier: retire this wave's LDS ops; leave global prefetches in flight.
#define RAWBAR() do {                                               \
    asm volatile("s_waitcnt lgkmcnt(0)" ::: "memory");              \
    __builtin_amdgcn_s_barrier();                                   \
    asm volatile("" ::: "memory"); } while (0)

// ---- pre-pass: build swizzled plain-bf16 BK=64 weight image + W2 bf16 --------
// image: 32 chunks (one weight x one 64-K range) of 16 KB:
//   [n][slot'] with slot' = s ^ (n & 7), s -> koff = (s>>2)*32 + (s&3)*8
// chunk id = fz*16 + kc. 32*8192 shorts = 512 KB; then W2 bf16 [128][128].
__global__ __launch_bounds__(256) void itemfusing_prep(
    const float* __restrict__ Wf1, const float* __restrict__ Wf2,
    const float* __restrict__ W2, short* __restrict__ wsp)
{
    const int t = blockIdx.x * 256 + threadIdx.x;
    if (t < 32768) {
        const int s  = t & 7;
        const int n  = (t >> 3) & 127;
        const int kc = (t >> 10) & 15;
        const int fz = (t >> 14) & 1;
        const int k  = kc * 64 + (s >> 2) * 32 + (s & 3) * 8;
        const float* src = (fz ? Wf2 : Wf1) + (size_t)n * 1024 + k;
        const int sp = s ^ (n & 7);
        *(s16x8*)(wsp + (size_t)(fz * 16 + kc) * 8192 + n * 64 + sp * 8)
            = cvt8(*(const f32x4*)src, *(const f32x4*)(src + 4));
    } else if (t < 32768 + 2048) {
        const int i = (t - 32768) * 8;
        const float* src = W2 + i;
        *(s16x8*)(wsp + 262144 + i) = cvt8(*(const f32x4*)src, *(const f32x4*)(src + 4));
    }
}

// ---- main: 256 thr = 4 waves = 2 sessions x 2 weights (fz-split).
// Wave (pr,fz): all 32 rows of session pr, ONE weight -> acc = 64 regs.
// ~190 regs/wave total -> 2 waves/SIMD -> TWO independent blocks per CU.
__global__ __launch_bounds__(THREADS, 2) void itemfusing_main(
    const float* __restrict__ inter, const float* __restrict__ intra,
    const float* __restrict__ bf1, const float* __restrict__ bf2,
    const float* __restrict__ W1,  const float* __restrict__ b1,
    const float* __restrict__ b2,
    const float* __restrict__ qw,  const float* __restrict__ qb,
    const float* __restrict__ W3,  const float* __restrict__ b3,
    const short* __restrict__ gimg, const short* __restrict__ w2b,
    float* __restrict__ out)
{
    __shared__ union {
        short wbuf[2][2][128][64];   // [buf][fz][n][kslot'] : 65536 B
        float fex[2][2][128][16];    // [pr][dir][n][r16]    : 65536 B
        short hbuf[2][32][HP];       // h rows, 2 sessions   : 17408 B
    } u;
    __shared__ float vnb [2][128];   // 1024 B
    __shared__ float w1vb[2][128];   // 1024 B
    __shared__ float sglp[2][2][128];// 2048 B   -> total 69632 B => 2 blocks/CU

    const int tid = threadIdx.x;
    const int l   = tid & 63;
    const int l15 = l & 15;
    const int kg  = l >> 4;
    const int w   = tid >> 6;
    const int pr  = w >> 1;      // session slot 0..1
    const int fz  = w & 1;       // 0: f1 (inter,Wf1)  1: f2 (intra,Wf2)
    const int sess = blockIdx.x * 2 + pr;
    const int m7  = l15 & 7;
    const int s0p = (kg ^ m7) * 8;          // ks=0 slot offset (shorts)
    const int s1p = ((4 + kg) ^ m7) * 8;    // ks=1 slot offset

    const float* Aemb = (fz ? intra : inter) + ((size_t)(sess * 32 + l15) * 1024 + kg * 8);
    short* wb = &u.wbuf[0][0][0][0];

    f32x4 accA[8], accB[8];    // m-tiles: rows 0-15 / 16-31 (own weight)
    #pragma unroll
    for (int nt = 0; nt < 8; ++nt) {
        accA[nt] = f32x4{0.f,0.f,0.f,0.f};
        accB[nt] = f32x4{0.f,0.f,0.f,0.f};
    }

    // staging: piece pf = tid>>7 (0: fz0 chunk, 1: fz1 chunk); lane-contiguous
    const int pf = tid >> 7;
    const int pt = tid & 127;
    const short* gsrc = gimg + (size_t)pf * 131072 + pt * 8;   // + kc*8192 + j*1024

    s16x8 wr0, wr1, wr2, wr3, wr4, wr5, wr6, wr7;
#define WLOADR(KC) do {                                                         \
    const short* p_ = gsrc + (size_t)(KC) * 8192;                               \
    wr0 = *(const s16x8*)p_;          wr1 = *(const s16x8*)(p_ + 1024);         \
    wr2 = *(const s16x8*)(p_ + 2048); wr3 = *(const s16x8*)(p_ + 3072);         \
    wr4 = *(const s16x8*)(p_ + 4096); wr5 = *(const s16x8*)(p_ + 5120);         \
    wr6 = *(const s16x8*)(p_ + 6144); wr7 = *(const s16x8*)(p_ + 7168); } while (0)
#define WSTORE(BUF) do {                                                        \
    short* d_ = wb + (BUF) * 16384 + pf * 8192 + pt * 8;                        \
    *(s16x8*)d_ = wr0;          *(s16x8*)(d_ + 1024) = wr1;                     \
    *(s16x8*)(d_ + 2048) = wr2; *(s16x8*)(d_ + 3072) = wr3;                     \
    *(s16x8*)(d_ + 4096) = wr4; *(s16x8*)(d_ + 5120) = wr5;                     \
    *(s16x8*)(d_ + 6144) = wr6; *(s16x8*)(d_ + 7168) = wr7; } while (0)

    // A regs: one named set per region parity (8 f32x4 each), own stream
    f32x4 Aa0, Aa1, Aa2, Aa3, Aa4, Aa5, Aa6, Aa7;
    f32x4 Ab0, Ab1, Ab2, Ab3, Ab4, Ab5, Ab6, Ab7;
#define ALOAD(S, KC) do {                                                       \
    const float* p_ = Aemb + (KC) * 64;                                         \
    S##0 = *(const f32x4*)p_;        S##1 = *(const f32x4*)(p_ + 4);            \
    S##2 = *(const f32x4*)(p_ + 32); S##3 = *(const f32x4*)(p_ + 36);           \
    const float* q_ = p_ + (size_t)16 * 1024;                                   \
    S##4 = *(const f32x4*)q_;        S##5 = *(const f32x4*)(q_ + 4);            \
    S##6 = *(const f32x4*)(q_ + 32); S##7 = *(const f32x4*)(q_ + 36); } while (0)

#define KSTEP(PB, AH0, AL0, AH1, AL1, SP) do {                                  \
    _Pragma("unroll")                                                           \
    for (int nt_ = 0; nt_ < 8; ++nt_) {                                         \
        s16x8 bh_ = *(const s16x8*)((PB) + nt_ * 1024 + (SP));                  \
        accA[nt_] = MFMA16(AH0, bh_, accA[nt_]);                                \
        accB[nt_] = MFMA16(AH1, bh_, accB[nt_]);                                \
        accA[nt_] = MFMA16(AL0, bh_, accA[nt_]);                                \
        accB[nt_] = MFMA16(AL1, bh_, accB[nt_]);                                \
    } } while (0)

#define COMPUTE(BUF, S) do {                                                    \
    const short* pb_ = wb + (BUF) * 16384 + fz * 8192 + l15 * 64;               \
    s16x8 ah0, al0, ah1, al1;                                                   \
    split8(S##0, S##1, ah0, al0);                                               \
    split8(S##4, S##5, ah1, al1);                                               \
    KSTEP(pb_, ah0, al0, ah1, al1, s0p);                                        \
    split8(S##2, S##3, ah0, al0);                                               \
    split8(S##6, S##7, ah1, al1);                                               \
    KSTEP(pb_, ah0, al0, ah1, al1, s1p);                                        \
    } while (0)

    // prologue: buf0 <- chunk0-pair; wr <- chunk1-pair; A for regions 0 and 1
    WLOADR(0); WSTORE(0);
    WLOADR(1);
    ALOAD(Aa, 0);
    ALOAD(Ab, 1);
    RAWBAR();

    // 16 regions of BK=64, one raw barrier each
    #pragma unroll 1
    for (int k2 = 0; k2 < 16; k2 += 2) {
        const bool more = (k2 < 14);
        {   // region k2 (buf0)
            WSTORE(1);
            if (more) WLOADR(k2 + 2);
            COMPUTE(0, Aa);
            if (more) ALOAD(Aa, k2 + 2);
        }
        RAWBAR();
        {   // region k2+1 (buf1)
            if (more) { WSTORE(0); WLOADR(k2 + 3); }
            COMPUTE(1, Ab);
            if (more) ALOAD(Ab, k2 + 3);
        }
        RAWBAR();
    }
#undef WLOADR
#undef WSTORE
#undef ALOAD
#undef KSTEP
#undef COMPUTE

    // ---------------- exchange: give paired wave its missing weight half ---------
    if (fz == 0) {
        #pragma unroll
        for (int nt = 0; nt < 8; ++nt)
            *(f32x4*)&u.fex[pr][0][nt * 16 + l15][kg * 4] = accB[nt];  // f1 rows 16-31
    } else {
        #pragma unroll
        for (int nt = 0; nt < 8; ++nt)
            *(f32x4*)&u.fex[pr][1][nt * 16 + l15][kg * 4] = accA[nt];  // f2 rows 0-15
    }
    __syncthreads();   // B1

    // ---------------- gate: h for own 16 rows (row = fz*16 + kg*4 + rj) ----------
    f32x4 hreg[8];
    #pragma unroll
    for (int nt = 0; nt < 8; ++nt) {
        const int n = nt * 16 + l15;
        f32x4 oth = *(const f32x4*)&u.fex[pr][1 - fz][n][kg * 4];
        f32x4 own = fz ? accB[nt] : accA[nt];
        const float bb1 = bf1[n], bb2 = bf2[n];
        #pragma unroll
        for (int rj = 0; rj < 4; ++rj) {
            float x1 = (fz ? oth[rj] : own[rj]) + bb1;
            float x2 = (fz ? own[rj] : oth[rj]) + bb2;
            float g  = sigm(x1 + x2);
            hreg[nt][rj] = x2 + g * (x1 - x2);
        }
    }
    // v_n (session row 31 = fz1 wave, kg=3, rj=3)
    if (fz == 1 && kg == 3) {
        #pragma unroll
        for (int nt = 0; nt < 8; ++nt) vnb[pr][nt * 16 + l15] = hreg[nt][3];
    }
    __syncthreads();   // B2: fex reads retired (union -> hbuf) + vn visible

    // ---------------- h rows -> hbuf (own 16 rows) + w1v -------------------------
    {
        short (*hb)[HP] = u.hbuf[pr];
        #pragma unroll
        for (int nt = 0; nt < 8; ++nt)
            #pragma unroll
            for (int rj = 0; rj < 4; ++rj)
                hb[fz * 16 + kg * 4 + rj][nt * 16 + l15] = f2b(hreg[nt][rj]);
    }
    {
        const int n = fz * 64 + l;
        const float* w1r = W1 + (size_t)n * 128;
        float a = b1[n];
        #pragma unroll
        for (int kk = 0; kk < 128; kk += 4) {
            f32x4 vv = *(const f32x4*)&vnb[pr][kk];
            f32x4 u0 = *(const f32x4*)(w1r + kk);
            #pragma unroll
            for (int j = 0; j < 4; ++j) a += u0[j] * vv[j];
        }
        w1vb[pr][n] = a;
    }
    __syncthreads();   // B3: hbuf + w1vb visible

    // ---------------- w2h = h @ W2^T (MFMA, own 16 rows) -------------------------
    f32x4 aw[8];
    #pragma unroll
    for (int nt = 0; nt < 8; ++nt) aw[nt] = f32x4{0.f, 0.f, 0.f, 0.f};
    {
        short (*hb)[HP] = u.hbuf[pr];
        #pragma unroll
        for (int ks = 0; ks < 4; ++ks) {
            const int kl = ks * 32 + kg * 8;
            s16x8 ah = *(const s16x8*)&hb[fz * 16 + l15][kl];
            #pragma unroll
            for (int nt = 0; nt < 8; ++nt) {
                s16x8 bw = *(const s16x8*)&w2b[(size_t)(nt * 16 + l15) * 128 + kl];
                aw[nt] = MFMA16(ah, bw, aw[nt]);
            }
        }
    }

    // ---------------- alpha rows (own 16 rows, wave-local) -----------------------
    float prt[4] = {0.f, 0.f, 0.f, 0.f};
    #pragma unroll
    for (int nt = 0; nt < 8; ++nt) {
        const int n = nt * 16 + l15;
        const float qn = qw[n], wv_ = w1vb[pr][n], bb = b2[n];
        #pragma unroll
        for (int rj = 0; rj < 4; ++rj)
            prt[rj] += qn * sigm(wv_ + aw[nt][rj] + bb);
    }
    const float qbias = qb[0];
    #pragma unroll
    for (int rj = 0; rj < 4; ++rj) {
        float v = prt[rj];
        v += __shfl_xor(v, 1); v += __shfl_xor(v, 2);
        v += __shfl_xor(v, 4); v += __shfl_xor(v, 8);
        prt[rj] = v + qbias;          // alpha for row fz*16 + kg*4 + rj
    }

    // ---------------- s_g partial over own 16 rows -------------------------------
    #pragma unroll
    for (int nt = 0; nt < 8; ++nt) {
        float sgv = 0.f;
        #pragma unroll
        for (int rj = 0; rj < 4; ++rj) sgv += prt[rj] * hreg[nt][rj];
        sgv += __shfl_xor(sgv, 16);
        sgv += __shfl_xor(sgv, 32);
        if (l < 16) sglp[pr][fz][nt * 16 + l15] = sgv;
    }
    __syncthreads();   // B4: sglp visible

    // ---------------- out = W3 @ [v_n ; s_g] + b3 --------------------------------
    {
        const int n = fz * 64 + l;
        const float* w3r = W3 + (size_t)n * 256;
        float o = b3[n];
        #pragma unroll
        for (int kk = 0; kk < 128; kk += 4) {
            f32x4 vv = *(const f32x4*)&vnb[pr][kk];
            f32x4 s0 = *(const f32x4*)&sglp[pr][0][kk];
            f32x4 s1 = *(const f32x4*)&sglp[pr][1][kk];
            f32x4 a0 = *(const f32x4*)(w3r + kk);
            f32x4 c0 = *(const f32x4*)(w3r + 128 + kk);
            #pragma unroll
            for (int j = 0; j < 4; ++j)
                o += a0[j] * vv[j] + c0[j] * (s0[j] + s1[j]);
        }
        out[(size_t)sess * 128 + n] = o;
    }
}

// ---- naive fallback (only if ws too small; correctness insurance) ------------
__global__ __launch_bounds__(128) void itemfusing_naive(
    const float* __restrict__ inter, const float* __restrict__ intra,
    const float* __restrict__ Wf1, const float* __restrict__ bf1,
    const float* __restrict__ Wf2, const float* __restrict__ bf2,
    const float* __restrict__ W1,  const float* __restrict__ b1,
    const float* __restrict__ W2,  const float* __restrict__ b2,
    const float* __restrict__ qw,  const float* __restrict__ qb,
    const float* __restrict__ W3,  const float* __restrict__ b3,
    float* __restrict__ out)
{
    __shared__ float h[32][128];
    __shared__ float vn[128], w1v[128], al[32], sg[128], red[128];
    const int n = threadIdx.x; const int sess = blockIdx.x;
    for (int t0 = 0; t0 < 32; ++t0) {
        const float* e1 = inter + (size_t)(sess * 32 + t0) * 1024;
        const float* e2 = intra + (size_t)(sess * 32 + t0) * 1024;
        const float* r1 = Wf1 + (size_t)n * 1024;
        const float* r2 = Wf2 + (size_t)n * 1024;
        float s1 = bf1[n], s2 = bf2[n];
        for (int k = 0; k < 1024; ++k) { s1 += e1[k] * r1[k]; s2 += e2[k] * r2[k]; }
        float g = sigm(s1 + s2);
        h[t0][n] = s2 + g * (s1 - s2);
    }
    __syncthreads();
    vn[n] = h[31][n];
    __syncthreads();
    { float a = b1[n]; const float* w1r = W1 + (size_t)n * 128;
      for (int k = 0; k < 128; ++k) a += w1r[k] * vn[k];
      w1v[n] = a; }
    __syncthreads();
    for (int t0 = 0; t0 < 32; ++t0) {
        float x = b2[n]; const float* w2r = W2 + (size_t)n * 128;
        for (int k = 0; k < 128; ++k) x += w2r[k] * h[t0][k];
        red[n] = qw[n] * sigm(w1v[n] + x); __syncthreads();
        for (int s_ = 64; s_ > 0; s_ >>= 1) { if (n < s_) red[n] += red[n + s_]; __syncthreads(); }
        if (n == 0) al[t0] = red[0] + qb[0];
        __syncthreads();
    }
    { float s = 0.f; for (int t0 = 0; t0 < 32; ++t0) s += al[t0] * h[t0][n];
      sg[n] = s; }
    __syncthreads();
    { float o = b3[n]; const float* w3r = W3 + (size_t)n * 256;
      for (int k = 0; k < 128; ++k) o += w3r[k] * vn[k] + w3r[128 + k] * sg[k];
      out[(size_t)sess * 128 + n] = o; }
}

extern "C" void kernel_launch(void* const* d_in, const int* in_sizes, int n_in,
                              void* d_out, int out_size, void* d_ws, size_t ws_size,
                              hipStream_t stream) {
    (void)n_in; (void)out_size;
    const float* inter = (const float*)d_in[0];
    const float* intra = (const float*)d_in[1];
    const float* Wf1   = (const float*)d_in[3];
    const float* bf1   = (const float*)d_in[4];
    const float* Wf2   = (const float*)d_in[5];
    const float* bf2   = (const float*)d_in[6];
    const float* W1    = (const float*)d_in[7];
    const float* b1    = (const float*)d_in[8];
    const float* W2    = (const float*)d_in[9];
    const float* b2    = (const float*)d_in[10];
    const float* qw    = (const float*)d_in[11];
    const float* qb    = (const float*)d_in[12];
    const float* W3    = (const float*)d_in[13];
    const float* b3    = (const float*)d_in[14];
    float* out = (float*)d_out;

    const int nsess = in_sizes[2];               // 4096
    const size_t WS_NEED = (size_t)(262144 + 16384) * sizeof(short);

    if (d_ws != nullptr && ws_size >= WS_NEED) {
        short* wsp = (short*)d_ws;
        itemfusing_prep<<<136, 256, 0, stream>>>(Wf1, Wf2, W2, wsp);
        itemfusing_main<<<nsess / 2, THREADS, 0, stream>>>(
            inter, intra, bf1, bf2, W1, b1, b2, qw, qb, W3, b3,
            wsp, wsp + 262144, out);
    } else {
        itemfusing_naive<<<nsess, 128, 0, stream>>>(
            inter, intra, Wf1, bf1, Wf2, bf2, W1, b1, W2, b2, qw, qb, W3, b3, out);
    }
}

// Round 14
// 323.195 us; speedup vs baseline: 1.2740x; 1.2740x over previous
//
#include <hip/hip_runtime.h>
#include <hip/hip_bf16.h>

#define THREADS 512
#define HP 136     // padded LDS row stride (shorts) for h rows

typedef float f32x4 __attribute__((ext_vector_type(4)));
typedef short s16x8 __attribute__((ext_vector_type(8)));

static __device__ __forceinline__ short f2b(float x) {
    return __builtin_bit_cast(short, __float2bfloat16(x));
}
static __device__ __forceinline__ float b2f(short u) {
    unsigned int v = ((unsigned int)(unsigned short)u) << 16;
    return __builtin_bit_cast(float, v);
}
static __device__ __forceinline__ void split8(const f32x4 a, const f32x4 b, s16x8& hi, s16x8& lo) {
    #pragma unroll
    for (int j = 0; j < 4; ++j) {
        short h0 = f2b(a[j]); hi[j]   = h0; lo[j]   = f2b(a[j] - b2f(h0));
        short h1 = f2b(b[j]); hi[j+4] = h1; lo[j+4] = f2b(b[j] - b2f(h1));
    }
}
static __device__ __forceinline__ s16x8 cvt8(const f32x4 a, const f32x4 b) {
    s16x8 r;
    r[0]=f2b(a[0]); r[1]=f2b(a[1]); r[2]=f2b(a[2]); r[3]=f2b(a[3]);
    r[4]=f2b(b[0]); r[5]=f2b(b[1]); r[6]=f2b(b[2]); r[7]=f2b(b[3]);
    return r;
}
static __device__ __forceinline__ float sigm(float x) { return 1.0f / (1.0f + __expf(-x)); }

#define MFMA16(A,B,C) __builtin_amdgcn_mfma_f32_16x16x32_bf16((A),(B),(C),0,0,0)

// Raw barrier: retire this wave's LDS ops; leave global prefetches in flight.
#define RAWBAR() do {                                               \
    asm volatile("s_waitcnt lgkmcnt(0)" ::: "memory");              \
    __builtin_amdgcn_s_barrier();                                   \
    asm volatile("" ::: "memory"); } while (0)

// ---- pre-pass: build swizzled plain-bf16 BK=64 weight image + W2 bf16 --------
// image: 32 chunks (one weight x one 64-K range) of 16 KB:
//   [n][slot'] with slot' = s ^ (n & 7), s -> koff = (s>>2)*32 + (s&3)*8
// chunk id = fz*16 + kc. 32*8192 shorts = 512 KB; then W2 bf16 [128][128].
__global__ __launch_bounds__(256) void itemfusing_prep(
    const float* __restrict__ Wf1, const float* __restrict__ Wf2,
    const float* __restrict__ W2, short* __restrict__ wsp)
{
    const int t = blockIdx.x * 256 + threadIdx.x;
    if (t < 32768) {
        const int s  = t & 7;
        const int n  = (t >> 3) & 127;
        const int kc = (t >> 10) & 15;
        const int fz = (t >> 14) & 1;
        const int k  = kc * 64 + (s >> 2) * 32 + (s & 3) * 8;
        const float* src = (fz ? Wf2 : Wf1) + (size_t)n * 1024 + k;
        const int sp = s ^ (n & 7);
        *(s16x8*)(wsp + (size_t)(fz * 16 + kc) * 8192 + n * 64 + sp * 8)
            = cvt8(*(const f32x4*)src, *(const f32x4*)(src + 4));
    } else if (t < 32768 + 2048) {
        const int i = (t - 32768) * 8;
        const float* src = W2 + i;
        *(s16x8*)(wsp + 262144 + i) = cvt8(*(const f32x4*)src, *(const f32x4*)(src + 4));
    }
}

// ---- main: 512 thr, 8 waves = 8 sessions, M=32/wave; 16 MERGED regions -------
// Region kc stages BOTH weights' BK=64 chunk (32 KB) and computes f1 AND f2:
// two independent 64-MFMA clusters per region, ONE barrier per region.
__global__ __launch_bounds__(THREADS, 2) void itemfusing_main(
    const float* __restrict__ inter, const float* __restrict__ intra,
    const float* __restrict__ bf1, const float* __restrict__ bf2,
    const float* __restrict__ W1,  const float* __restrict__ b1,
    const float* __restrict__ b2,
    const float* __restrict__ qw,  const float* __restrict__ qb,
    const float* __restrict__ W3,  const float* __restrict__ b3,
    const short* __restrict__ gimg, const short* __restrict__ w2b,
    float* __restrict__ out)
{
    __shared__ union {
        short wbuf[2][2][128][64];       // [buf][fz][n][kslot'] : 65536 B
        struct {
            short hbuf[4][32][HP];       // 34816 B
            float vn [8][128];           // 4096 B
            float w1v[8][128];           // 4096 B
            float sgl[8][128];           // 4096 B
        } t;                             // 47104 B
    } u;                                 // static total 65536 B

    const int tid = threadIdx.x;
    const int w   = tid >> 6;        // wave id == session slot (0..7)
    const int l   = tid & 63;
    const int l15 = l & 15;
    const int kg  = l >> 4;
    const int sess = blockIdx.x * 8 + w;
    const int row0 = sess * 32;
    const int m7  = l15 & 7;
    const int s0p = (kg ^ m7) * 8;          // ks=0 slot offset (shorts)
    const int s1p = ((4 + kg) ^ m7) * 8;    // ks=1 slot offset

    const float* A1 = inter + (size_t)(row0 + l15) * 1024 + kg * 8;
    const float* A2 = intra + (size_t)(row0 + l15) * 1024 + kg * 8;
    short* wb = &u.wbuf[0][0][0][0];

    f32x4 acc1[2][8], acc2[2][8];
    #pragma unroll
    for (int mt = 0; mt < 2; ++mt)
        #pragma unroll
        for (int nt = 0; nt < 8; ++nt) {
            acc1[mt][nt] = f32x4{0.f,0.f,0.f,0.f};
            acc2[mt][nt] = f32x4{0.f,0.f,0.f,0.f};
        }

    // staging: 4 lane-contiguous 8 KB pieces (pieces 0,1 = fz0; 2,3 = fz1)
    s16x8 wr0, wr1, wr2, wr3;
#define WLOADR(KC) do {                                                         \
    const short* p0_ = gimg + (size_t)(KC) * 8192 + tid * 8;                    \
    const short* p1_ = gimg + (size_t)(16 + (KC)) * 8192 + tid * 8;             \
    wr0 = *(const s16x8*)p0_;          wr1 = *(const s16x8*)(p0_ + 4096);       \
    wr2 = *(const s16x8*)p1_;          wr3 = *(const s16x8*)(p1_ + 4096); } while (0)
#define WSTORE(BUF) do {                                                        \
    short* d_ = wb + (BUF) * 16384 + tid * 8;                                   \
    *(s16x8*)d_ = wr0;           *(s16x8*)(d_ + 4096) = wr1;                    \
    *(s16x8*)(d_ + 8192) = wr2;  *(s16x8*)(d_ + 12288) = wr3; } while (0)

    // A regs: one named set per stream (8 f32x4 each), reloaded each region
    f32x4 AE0, AE1, AE2, AE3, AE4, AE5, AE6, AE7;   // inter (f1)
    f32x4 AO0, AO1, AO2, AO3, AO4, AO5, AO6, AO7;   // intra (f2)
#define ALOAD(S, AP, KC) do {                                                   \
    const float* p_ = (AP) + (KC) * 64;                                         \
    S##0 = *(const f32x4*)p_;        S##1 = *(const f32x4*)(p_ + 4);            \
    S##2 = *(const f32x4*)(p_ + 32); S##3 = *(const f32x4*)(p_ + 36);           \
    const float* q_ = p_ + (size_t)16 * 1024;                                   \
    S##4 = *(const f32x4*)q_;        S##5 = *(const f32x4*)(q_ + 4);            \
    S##6 = *(const f32x4*)(q_ + 32); S##7 = *(const f32x4*)(q_ + 36); } while (0)

#define KSTEP(PB, ACC, AH0, AH1, AL0, AL1, SP) do {                             \
    _Pragma("unroll")                                                           \
    for (int nt_ = 0; nt_ < 8; ++nt_) {                                         \
        s16x8 bh_ = *(const s16x8*)((PB) + nt_ * 1024 + (SP));                  \
        ACC[0][nt_] = MFMA16(AH0, bh_, ACC[0][nt_]);                            \
        ACC[1][nt_] = MFMA16(AH1, bh_, ACC[1][nt_]);                            \
        ACC[0][nt_] = MFMA16(AL0, bh_, ACC[0][nt_]);                            \
        ACC[1][nt_] = MFMA16(AL1, bh_, ACC[1][nt_]);                            \
    } } while (0)

#define COMPUTE(BUF, FZ, ACC, S) do {                                           \
    const short* pb_ = wb + (BUF) * 16384 + (FZ) * 8192 + l15 * 64;             \
    s16x8 ah0, al0, ah1, al1;                                                   \
    split8(S##0, S##1, ah0, al0);                                               \
    split8(S##4, S##5, ah1, al1);                                               \
    KSTEP(pb_, ACC, ah0, ah1, al0, al1, s0p);                                   \
    split8(S##2, S##3, ah0, al0);                                               \
    split8(S##6, S##7, ah1, al1);                                               \
    KSTEP(pb_, ACC, ah0, ah1, al0, al1, s1p);                                   \
    } while (0)

    // prologue: buf0 <- chunk0 (both weights); regs <- chunk1; A for region 0
    WLOADR(0); WSTORE(0);
    WLOADR(1);
    ALOAD(AE, A1, 0);
    ALOAD(AO, A2, 0);
    RAWBAR();

    // 16 merged regions, one barrier each
    #pragma unroll 1
    for (int kc = 0; kc < 16; ++kc) {
        const bool more = (kc < 15);
        if (more) WSTORE((kc + 1) & 1);       // stage chunk kc+1
        if (kc < 14) WLOADR(kc + 2);          // prefetch chunk kc+2
        COMPUTE(kc & 1, 0, acc1, AE);         // f1 cluster (64 MFMA)
        if (more) ALOAD(AE, A1, kc + 1);
        COMPUTE(kc & 1, 1, acc2, AO);         // f2 cluster (64 MFMA, independent)
        if (more) ALOAD(AO, A2, kc + 1);
        RAWBAR();
    }
#undef WLOADR
#undef WSTORE
#undef ALOAD
#undef KSTEP
#undef COMPUTE

    // ---------------- phase 2: bias + gate -> h (fp32, kept in acc1) ----------
    #pragma unroll
    for (int nt = 0; nt < 8; ++nt) {
        const int n = nt * 16 + l15;
        const float bb1 = bf1[n], bb2 = bf2[n];
        #pragma unroll
        for (int mt = 0; mt < 2; ++mt)
            #pragma unroll
            for (int rj = 0; rj < 4; ++rj) {
                float x1 = acc1[mt][nt][rj] + bb1;
                float x2 = acc2[mt][nt][rj] + bb2;
                float g  = sigm(x1 + x2);
                acc1[mt][nt][rj] = x2 + g * (x1 - x2);
            }
    }

    // v_n (session row 31: mt=1, kg=3, rj=3)
    if (kg == 3) {
        #pragma unroll
        for (int nt = 0; nt < 8; ++nt) u.t.vn[w][nt * 16 + l15] = acc1[1][nt][3];
    }
    asm volatile("s_waitcnt lgkmcnt(0)" ::: "memory");

    // ---------------- phase 3: w1v = W1 @ v_n + b1 (per session, wave-local) --
    {
        const int n0 = l, n1 = l + 64;
        const float* w1r0 = W1 + (size_t)n0 * 128;
        const float* w1r1 = W1 + (size_t)n1 * 128;
        float s0 = 0.f, s1 = 0.f;
        #pragma unroll
        for (int kk = 0; kk < 128; kk += 4) {
            f32x4 vv = *(const f32x4*)&u.t.vn[w][kk];
            f32x4 u0 = *(const f32x4*)(w1r0 + kk);
            f32x4 u1 = *(const f32x4*)(w1r1 + kk);
            #pragma unroll
            for (int j = 0; j < 4; ++j) { s0 += u0[j] * vv[j]; s1 += u1[j] * vv[j]; }
        }
        u.t.w1v[w][n0] = s0 + b1[n0];
        u.t.w1v[w][n1] = s1 + b1[n1];
    }
    asm volatile("s_waitcnt lgkmcnt(0)" ::: "memory");

    // ---------------- phases 4-7 per wave (hbuf round-split: 4 waves then 4) --
    auto tail = [&](int wj) {
        short (*hb)[HP] = u.t.hbuf[wj];
        #pragma unroll
        for (int nt = 0; nt < 8; ++nt)
            #pragma unroll
            for (int mt = 0; mt < 2; ++mt)
                #pragma unroll
                for (int rj = 0; rj < 4; ++rj)
                    hb[16 * mt + kg * 4 + rj][nt * 16 + l15] = f2b(acc1[mt][nt][rj]);
        asm volatile("s_waitcnt lgkmcnt(0)" ::: "memory");

        // phase 4: w2h = h @ W2^T (bf16 MFMA, K=128)
        f32x4 accw[2][8];
        #pragma unroll
        for (int mt = 0; mt < 2; ++mt)
            #pragma unroll
            for (int nt = 0; nt < 8; ++nt) accw[mt][nt] = f32x4{0.f,0.f,0.f,0.f};
        #pragma unroll
        for (int ks = 0; ks < 4; ++ks) {
            const int kl = ks * 32 + kg * 8;
            s16x8 ah0 = *(const s16x8*)&hb[l15][kl];
            s16x8 ah1 = *(const s16x8*)&hb[16 + l15][kl];
            #pragma unroll
            for (int nt = 0; nt < 8; ++nt) {
                s16x8 bw = *(const s16x8*)&w2b[(size_t)(nt * 16 + l15) * 128 + kl];
                accw[0][nt] = MFMA16(ah0, bw, accw[0][nt]);
                accw[1][nt] = MFMA16(ah1, bw, accw[1][nt]);
            }
        }

        // phase 5: alpha[row] = qb + sum_n q_n * sigm(w1v_n + w2h + b2_n)
        float part[2][4];
        #pragma unroll
        for (int mt = 0; mt < 2; ++mt)
            #pragma unroll
            for (int rj = 0; rj < 4; ++rj) part[mt][rj] = 0.f;
        #pragma unroll
        for (int nt = 0; nt < 8; ++nt) {
            const int n = nt * 16 + l15;
            const float qn = qw[n], wv_ = u.t.w1v[w][n], bb = b2[n];
            #pragma unroll
            for (int mt = 0; mt < 2; ++mt)
                #pragma unroll
                for (int rj = 0; rj < 4; ++rj)
                    part[mt][rj] += qn * sigm(wv_ + accw[mt][nt][rj] + bb);
        }
        const float qbias = qb[0];
        #pragma unroll
        for (int mt = 0; mt < 2; ++mt)
            #pragma unroll
            for (int rj = 0; rj < 4; ++rj) {
                float v = part[mt][rj];
                v += __shfl_xor(v, 1); v += __shfl_xor(v, 2);
                v += __shfl_xor(v, 4); v += __shfl_xor(v, 8);
                part[mt][rj] = v + qbias;      // alpha for row 16*mt + kg*4 + rj
            }

        // phase 6: s_g[n] = sum_t alpha_t * h[t][n]  (fp32, in-register + shfl)
        #pragma unroll
        for (int nt = 0; nt < 8; ++nt) {
            float s = 0.f;
            #pragma unroll
            for (int mt = 0; mt < 2; ++mt)
                #pragma unroll
                for (int rj = 0; rj < 4; ++rj)
                    s += part[mt][rj] * acc1[mt][nt][rj];
            s += __shfl_xor(s, 16);
            s += __shfl_xor(s, 32);
            if (l < 16) u.t.sgl[w][nt * 16 + l15] = s;
        }
        asm volatile("s_waitcnt lgkmcnt(0)" ::: "memory");

        // phase 7: out = W3 @ [v_n ; s_g] + b3  (fp32)
        const int n0 = l, n1 = l + 64;
        const float* w3r0 = W3 + (size_t)n0 * 256;
        const float* w3r1 = W3 + (size_t)n1 * 256;
        float h0 = b3[n0], h1 = b3[n1];
        #pragma unroll
        for (int kk = 0; kk < 128; kk += 4) {
            f32x4 vv = *(const f32x4*)&u.t.vn[w][kk];
            f32x4 ss = *(const f32x4*)&u.t.sgl[w][kk];
            f32x4 a0 = *(const f32x4*)(w3r0 + kk);
            f32x4 a1 = *(const f32x4*)(w3r1 + kk);
            f32x4 c0 = *(const f32x4*)(w3r0 + 128 + kk);
            f32x4 c1 = *(const f32x4*)(w3r1 + 128 + kk);
            #pragma unroll
            for (int j = 0; j < 4; ++j) {
                h0 += a0[j] * vv[j] + c0[j] * ss[j];
                h1 += a1[j] * vv[j] + c1[j] * ss[j];
            }
        }
        out[(size_t)sess * 128 + n0] = h0;
        out[(size_t)sess * 128 + n1] = h1;
    };

    if (w < 4) tail(w);
    __syncthreads();          // round A readers done before round B overwrites hbuf
    if (w >= 4) tail(w - 4);
}

// ---- naive fallback (only if ws too small; correctness insurance) ------------
__global__ __launch_bounds__(128) void itemfusing_naive(
    const float* __restrict__ inter, const float* __restrict__ intra,
    const float* __restrict__ Wf1, const float* __restrict__ bf1,
    const float* __restrict__ Wf2, const float* __restrict__ bf2,
    const float* __restrict__ W1,  const float* __restrict__ b1,
    const float* __restrict__ W2,  const float* __restrict__ b2,
    const float* __restrict__ qw,  const float* __restrict__ qb,
    const float* __restrict__ W3,  const float* __restrict__ b3,
    float* __restrict__ out)
{
    __shared__ float h[32][128];
    __shared__ float vn[128], w1v[128], al[32], sg[128], red[128];
    const int n = threadIdx.x; const int sess = blockIdx.x;
    for (int t0 = 0; t0 < 32; ++t0) {
        const float* e1 = inter + (size_t)(sess * 32 + t0) * 1024;
        const float* e2 = intra + (size_t)(sess * 32 + t0) * 1024;
        const float* r1 = Wf1 + (size_t)n * 1024;
        const float* r2 = Wf2 + (size_t)n * 1024;
        float s1 = bf1[n], s2 = bf2[n];
        for (int k = 0; k < 1024; ++k) { s1 += e1[k] * r1[k]; s2 += e2[k] * r2[k]; }
        float g = sigm(s1 + s2);
        h[t0][n] = s2 + g * (s1 - s2);
    }
    __syncthreads();
    vn[n] = h[31][n];
    __syncthreads();
    { float a = b1[n]; const float* w1r = W1 + (size_t)n * 128;
      for (int k = 0; k < 128; ++k) a += w1r[k] * vn[k];
      w1v[n] = a; }
    __syncthreads();
    for (int t0 = 0; t0 < 32; ++t0) {
        float x = b2[n]; const float* w2r = W2 + (size_t)n * 128;
        for (int k = 0; k < 128; ++k) x += w2r[k] * h[t0][k];
        red[n] = qw[n] * sigm(w1v[n] + x); __syncthreads();
        for (int s_ = 64; s_ > 0; s_ >>= 1) { if (n < s_) red[n] += red[n + s_]; __syncthreads(); }
        if (n == 0) al[t0] = red[0] + qb[0];
        __syncthreads();
    }
    { float s = 0.f; for (int t0 = 0; t0 < 32; ++t0) s += al[t0] * h[t0][n];
      sg[n] = s; }
    __syncthreads();
    { float o = b3[n]; const float* w3r = W3 + (size_t)n * 256;
      for (int k = 0; k < 128; ++k) o += w3r[k] * vn[k] + w3r[128 + k] * sg[k];
      out[(size_t)sess * 128 + n] = o; }
}

extern "C" void kernel_launch(void* const* d_in, const int* in_sizes, int n_in,
                              void* d_out, int out_size, void* d_ws, size_t ws_size,
                              hipStream_t stream) {
    (void)n_in; (void)out_size;
    const float* inter = (const float*)d_in[0];
    const float* intra = (const float*)d_in[1];
    const float* Wf1   = (const float*)d_in[3];
    const float* bf1   = (const float*)d_in[4];
    const float* Wf2   = (const float*)d_in[5];
    const float* bf2   = (const float*)d_in[6];
    const float* W1    = (const float*)d_in[7];
    const float* b1    = (const float*)d_in[8];
    const float* W2    = (const float*)d_in[9];
    const float* b2    = (const float*)d_in[10];
    const float* qw    = (const float*)d_in[11];
    const float* qb    = (const float*)d_in[12];
    const float* W3    = (const float*)d_in[13];
    const float* b3    = (const float*)d_in[14];
    float* out = (float*)d_out;

    const int nsess = in_sizes[2];               // 4096
    const size_t WS_NEED = (size_t)(262144 + 16384) * sizeof(short);

    if (d_ws != nullptr && ws_size >= WS_NEED) {
        short* wsp = (short*)d_ws;
        itemfusing_prep<<<136, 256, 0, stream>>>(Wf1, Wf2, W2, wsp);
        itemfusing_main<<<nsess / 8, THREADS, 0, stream>>>(
            inter, intra, bf1, bf2, W1, b1, b2, qw, qb, W3, b3,
            wsp, wsp + 262144, out);
    } else {
        itemfusing_naive<<<nsess, 128, 0, stream>>>(
            inter, intra, Wf1, bf1, Wf2, bf2, W1, b1, W2, b2, qw, qb, W3, b3, out);
    }
}